// Round 17
// baseline (256.212 us; speedup 1.0000x reference)
//
#include <hip/hip_runtime.h>

// Sub4BitLinear: y = X[M,K] @ W[N,K]^T, M=8192 N=4096 K=4096
// int8 path: (1) per-row quant x -> i8 + sx, (2) per-row quant codebook W -> i8 + sw,
// (3) 256x256 8-phase i8 MFMA GEMM with SUBTILE-SKEWED reads (m201-style):
//     phase p reads exactly the one operand subtile phase p+1 needs (snake
//     quadrant order), so MFMA starts with operands in registers and reads
//     drain under the MFMA burst. Zero extra registers vs R9.

#define M_DIM 8192
#define N_DIM 4096
#define K_DIM 4096
#define BK 128              // i8 elements per K-tile (128 B/row)
#define NKT (K_DIM / BK)    // 32 K-tiles

typedef __attribute__((ext_vector_type(4))) int int32x4;

#define AS1 __attribute__((address_space(1)))
#define AS3 __attribute__((address_space(3)))

__device__ __forceinline__ void gl_lds16(const void* g, void* l) {
    __builtin_amdgcn_global_load_lds((const AS1 void*)g, (AS3 void*)l, 16, 0, 0);
}

// ---------------- kernel 1: per-row quantize x -> int8 ----------------
__global__ __launch_bounds__(256) void quant_x(const float* __restrict__ X,
                                               char* __restrict__ XQ,
                                               float* __restrict__ SX) {
    const int row = blockIdx.x;
    const int t = threadIdx.x;
    const float4* xp = (const float4*)(X + (size_t)row * K_DIM);
    float4 v[4];
    float mx = 0.0f;
#pragma unroll
    for (int i = 0; i < 4; ++i) {
        v[i] = xp[t * 4 + i];
        mx = fmaxf(mx, fmaxf(fmaxf(fabsf(v[i].x), fabsf(v[i].y)),
                             fmaxf(fabsf(v[i].z), fabsf(v[i].w))));
    }
#pragma unroll
    for (int off = 1; off < 64; off <<= 1)
        mx = fmaxf(mx, __shfl_xor(mx, off));
    __shared__ float wmx[4];
    if ((t & 63) == 0) wmx[t >> 6] = mx;
    __syncthreads();
    mx = fmaxf(fmaxf(wmx[0], wmx[1]), fmaxf(wmx[2], wmx[3]));
    const float inv = 127.0f / mx;
    int4 o4;
    int* po = (int*)&o4;
#pragma unroll
    for (int i = 0; i < 4; ++i) {
        int q0 = (int)rintf(v[i].x * inv);
        int q1 = (int)rintf(v[i].y * inv);
        int q2 = (int)rintf(v[i].z * inv);
        int q3 = (int)rintf(v[i].w * inv);
        po[i] = (q0 & 255) | ((q1 & 255) << 8) | ((q2 & 255) << 16) | ((q3 & 255) << 24);
    }
    ((int4*)(XQ + (size_t)row * K_DIM))[t] = o4;
    if (t == 0) SX[row] = mx * (1.0f / 127.0f);
}

// ---------------- kernel 2: per-row quantize codebook W -> int8 ----------------
__global__ __launch_bounds__(256) void quant_w(const int* __restrict__ CD,
                                               const float* __restrict__ G,
                                               char* __restrict__ WQ,
                                               float* __restrict__ SW) {
    const int o = blockIdx.x;
    __shared__ int gq[8];
    if (threadIdx.x == 0) {
        float g[8], mx = 0.0f;
#pragma unroll
        for (int j = 0; j < 8; ++j) { g[j] = G[o * 8 + j]; mx = fmaxf(mx, fabsf(g[j])); }
        mx = fmaxf(mx, 1e-20f);
        const float inv = 127.0f / mx;
        SW[o] = mx * (1.0f / 127.0f);
#pragma unroll
        for (int j = 0; j < 8; ++j) gq[j] = ((int)rintf(g[j] * inv)) & 255;
    }
    __syncthreads();
    const int4* cp = (const int4*)(CD + (size_t)o * K_DIM);
    int* wp = (int*)(WQ + (size_t)o * K_DIM);
#pragma unroll
    for (int r = 0; r < 4; ++r) {
        int idx = r * 256 + threadIdx.x;
        int4 c = cp[idx];
        wp[idx] = gq[c.x] | (gq[c.y] << 8) | (gq[c.z] << 16) | (gq[c.w] << 24);
    }
}

// ---------------- kernel 3: 256x256 8-phase skewed-subtile i8 GEMM ----------------
// 512 threads = 8 waves (2M x 4N); per-wave 128x64 = acc[8][4] i32 frags.
// LDS [buf][half][128x128B], XOR-swizzled (byte ^= (row&7)<<4), same as R9.
// Snake quadrants per tile: (0,0)->(0,1)->(1,1)->(1,0); reads one subtile
// ahead: p1 fb1<-e.Bh1 | p2 fa1<-e.Ah1 | p3 fa0<-o.Ah0 | p4 fb0<-o.Bh0(post-MF)
// p5 fb1<-o.Bh1 | p6 fa1<-o.Ah1 | p7 fa0<-e2.Ah0 | p8 fb0<-e2.Bh0(post-MF).
// Publishes: vmcnt(0)+barrier at p2-end (tile o) and p6-end (tile e2) --
// queue then holds exactly that tile's 8 loads (1.7-3 phases old, ~free).
// Stages: p1 o.B0 | p3 e2.A0 | p4 e2.B1 | p5 e2.A1,e2.B0 | p7 o2.A0 |
// p8 o2.A1,o2.B1. All STGs >=1 barrier after their region's last-load drain.
__global__ __launch_bounds__(512, 2) void gemm8(const char* __restrict__ A,
                                                const char* __restrict__ B,
                                                const float* __restrict__ SX,
                                                const float* __restrict__ SW,
                                                float* __restrict__ C) {
    __shared__ char As[2][2][128 * 128];
    __shared__ char Bs[2][2][128 * 128];

    const int tid = threadIdx.x;
    const int lane = tid & 63;
    const int wid = tid >> 6;
    const int wm = wid >> 2;        // 0..1: wave's M half
    const int wn = wid & 3;         // 0..3: wave's N slice
    const int bh = wn >> 1;         // B half-buffer

    // XCD-bijective block swizzle (nwg = 512, %8 == 0)
    int wg = blockIdx.x;
    wg = (wg & 7) * (gridDim.x >> 3) + (wg >> 3);
    const int ntn = N_DIM / 256;    // 16
    const int bm = (wg / ntn) * 256;
    const int bn = (wg % ntn) * 256;

    // fragment read lane constants (byte units):
    const int fr = lane & 15;
    const int swzb = (fr & 7) << 4;
    const int offk0 = fr * 128 + (((lane >> 4) << 4) ^ swzb);
    const int offk1 = offk0 ^ 64;
    const int bwoffB = (wn & 1) * 8192;

    // staging: chunk c = tid; row=c>>3 (+64 2nd instr), slot=(c&7)^(row&7), 16B
    const int row0 = tid >> 3;
    const int sl = (((tid & 7) ^ (row0 & 7)) << 4);

#define STG(GP, RB, KT, LD) do {                                                   \
        const int kb_ = (((KT) < NKT) ? (KT) : 0) * BK;                            \
        gl_lds16((GP) + (size_t)((RB) + row0) * K_DIM + kb_ + sl,                  \
                 (LD) + wid * 1024);                                               \
        gl_lds16((GP) + (size_t)((RB) + row0 + 64) * K_DIM + kb_ + sl,             \
                 (LD) + 8192 + wid * 1024);                                        \
    } while (0)

// read one A subtile (8 x b128) into named set FA; MH = quarter within half
#define RDA(FA, B_, MH_)                                                           \
    _Pragma("unroll") for (int m = 0; m < 4; ++m) {                                \
        FA[m * 2 + 0] = *(const int32x4*)&As[B_][wm][(MH_) * 8192 + m * 2048 + offk0]; \
        FA[m * 2 + 1] = *(const int32x4*)&As[B_][wm][(MH_) * 8192 + m * 2048 + offk1]; \
    }

// read one B subtile (4 x b128) into named set FB
#define RDB(FB, B_, NH_)                                                           \
    _Pragma("unroll") for (int n = 0; n < 2; ++n) {                                \
        FB[n * 2 + 0] = *(const int32x4*)&Bs[B_][bh][bwoffB + (NH_) * 4096 + n * 2048 + offk0]; \
        FB[n * 2 + 1] = *(const int32x4*)&Bs[B_][bh][bwoffB + (NH_) * 4096 + n * 2048 + offk1]; \
    }

// one quadrant: 16 MFMA from named sets (operands loaded >=1 phase ago)
#define MFQ(FA, FB, MH_, NH_)                                                      \
    __builtin_amdgcn_s_setprio(1);                                                 \
    _Pragma("unroll") for (int ks = 0; ks < 2; ++ks)                               \
    _Pragma("unroll") for (int m = 0; m < 4; ++m)                                  \
    _Pragma("unroll") for (int n = 0; n < 2; ++n)                                  \
        acc[(MH_) * 4 + m][(NH_) * 2 + n] = __builtin_amdgcn_mfma_i32_16x16x64_i8( \
            FA[m * 2 + ks], FB[n * 2 + ks],                                        \
            acc[(MH_) * 4 + m][(NH_) * 2 + n], 0, 0, 0);                           \
    __builtin_amdgcn_s_setprio(0);

#define FENCE __builtin_amdgcn_sched_barrier(0);
#define BAR   __builtin_amdgcn_s_barrier();
#define VM0   asm volatile("s_waitcnt vmcnt(0)" ::: "memory");

    int32x4 acc[8][4] = {};
    int32x4 fa0[8], fa1[8];
    int32x4 fb0[4], fb1[4];

    // prologue: tile0 full (B0,B1,A0,A1) + tile1 {A0,A1,B1}; vmcnt(6) drains
    // tile0's 8; pre-read fa0<-t0.Ah0, fb0<-t0.Bh0 for p1.
    STG(B, bn,       0, &Bs[0][0][0]);
    STG(B, bn + 128, 0, &Bs[0][1][0]);
    STG(A, bm,       0, &As[0][0][0]);
    STG(A, bm + 128, 0, &As[0][1][0]);
    STG(A, bm,       1, &As[1][0][0]);
    STG(A, bm + 128, 1, &As[1][1][0]);
    STG(B, bn + 128, 1, &Bs[1][1][0]);
    asm volatile("s_waitcnt vmcnt(6)" ::: "memory");
    BAR
    RDA(fa0, 0, 0)
    RDB(fb0, 0, 0)

    for (int j = 0; j < NKT / 2; ++j) {
        const int o = 2 * j + 1, e2 = 2 * j + 2, o2 = 2 * j + 3;
        // p1: rd fb1<-e.Bh1; stage o.B0; MF e(0,0)
        STG(B, bn, o, &Bs[1][0][0]);
        RDB(fb1, 0, 1)
        MFQ(fa0, fb0, 0, 0) FENCE BAR
        // p2: rd fa1<-e.Ah1; MF e(0,1); publish tile o (vmcnt(0))
        RDA(fa1, 0, 1)
        MFQ(fa0, fb1, 0, 1) FENCE VM0 BAR
        // p3: rd fa0<-o.Ah0; stage e2.A0; MF e(1,1)
        STG(A, bm, e2, &As[0][0][0]);
        RDA(fa0, 1, 0)
        MFQ(fa1, fb1, 1, 1) FENCE BAR
        // p4: MF e(1,0); THEN rd fb0<-o.Bh0 (WAR, C++ order after); stage e2.B1
        STG(B, bn + 128, e2, &Bs[0][1][0]);
        MFQ(fa1, fb0, 1, 0)
        RDB(fb0, 1, 0)
        FENCE BAR
        // p5: rd fb1<-o.Bh1; stage e2.A1, e2.B0; MF o(0,0)
        STG(A, bm + 128, e2, &As[0][1][0]);
        STG(B, bn, e2, &Bs[0][0][0]);
        RDB(fb1, 1, 1)
        MFQ(fa0, fb0, 0, 0) FENCE BAR
        // p6: rd fa1<-o.Ah1; MF o(0,1); publish tile e2 (vmcnt(0))
        RDA(fa1, 1, 1)
        MFQ(fa0, fb1, 0, 1) FENCE VM0 BAR
        // p7: rd fa0<-e2.Ah0; stage o2.A0; MF o(1,1)
        STG(A, bm, o2, &As[1][0][0]);
        RDA(fa0, 0, 0)
        MFQ(fa1, fb1, 1, 1) FENCE BAR
        // p8: MF o(1,0); THEN rd fb0<-e2.Bh0; stage o2.A1, o2.B1
        STG(A, bm + 128, o2, &As[1][1][0]);
        STG(B, bn + 128, o2, &Bs[1][1][0]);
        MFQ(fa1, fb0, 1, 0)
        RDB(fb0, 0, 0)
        FENCE BAR
    }
    VM0

    // C-write with scales: row = (lane>>4)*4 + r, col = lane&15 per 16x16 frag
    const int crow0 = bm + wm * 128 + ((lane >> 4) << 2);
    const int ccol0 = bn + wn * 64 + (lane & 15);
    float swc[4];
#pragma unroll
    for (int ni = 0; ni < 4; ++ni) swc[ni] = SW[ccol0 + ni * 16];
#pragma unroll
    for (int mi = 0; mi < 8; ++mi)
#pragma unroll
        for (int r = 0; r < 4; ++r) {
            const float sxr = SX[crow0 + mi * 16 + r];
#pragma unroll
            for (int ni = 0; ni < 4; ++ni)
                C[(size_t)(crow0 + mi * 16 + r) * N_DIM + ccol0 + ni * 16] =
                    (float)acc[mi][ni][r] * sxr * swc[ni];
        }
}

// ---------------- fallback: tiled f32 GEMM with on-the-fly dequant ----------------
__global__ __launch_bounds__(256) void fb_gemm(const float* __restrict__ X,
                                               const float* __restrict__ G,
                                               const int* __restrict__ CD,
                                               float* __restrict__ Y) {
    __shared__ float xs[16][64];
    __shared__ float ws[16][64];
    const int bm = blockIdx.y << 6, bn = blockIdx.x << 6;
    const int tid = threadIdx.x;
    const int tn = tid & 15, tm = tid >> 4;
    float acc[4][4] = {};
    for (int k0 = 0; k0 < K_DIM; k0 += 16) {
#pragma unroll
        for (int r = 0; r < 4; ++r) {
            int e = r * 256 + tid;
            int mm = e >> 4, kk = e & 15;
            xs[kk][mm] = X[(size_t)(bm + mm) * K_DIM + k0 + kk];
            int code = CD[(size_t)(bn + mm) * K_DIM + k0 + kk];
            ws[kk][mm] = G[(bn + mm) * 8 + code];
        }
        __syncthreads();
#pragma unroll
        for (int kk = 0; kk < 16; ++kk)
#pragma unroll
            for (int i = 0; i < 4; ++i)
#pragma unroll
                for (int j = 0; j < 4; ++j)
                    acc[i][j] += xs[kk][tm * 4 + i] * ws[kk][tn * 4 + j];
        __syncthreads();
    }
#pragma unroll
    for (int i = 0; i < 4; ++i)
#pragma unroll
        for (int j = 0; j < 4; ++j)
            Y[(size_t)(bm + tm * 4 + i) * N_DIM + bn + tn * 4 + j] = acc[i][j];
}

extern "C" void kernel_launch(void* const* d_in, const int* in_sizes, int n_in,
                              void* d_out, int out_size, void* d_ws, size_t ws_size,
                              hipStream_t stream) {
    const float* x = (const float*)d_in[0];
    const float* qg = (const float*)d_in[1];
    const int* wc = (const int*)d_in[2];
    float* y = (float*)d_out;

    // workspace: sx[8192] f32 | sw[4096] f32 | xq[8192*4096] i8 | wq[4096*4096] i8
    const size_t sx_off = 0;
    const size_t sw_off = (size_t)M_DIM * 4;
    const size_t xq_off = (size_t)(M_DIM + N_DIM) * 4;
    const size_t wq_off = xq_off + (size_t)M_DIM * K_DIM;
    const size_t need = wq_off + (size_t)N_DIM * K_DIM;

    if (ws_size >= need) {
        float* sx = (float*)((char*)d_ws + sx_off);
        float* sw = (float*)((char*)d_ws + sw_off);
        char* xq = (char*)d_ws + xq_off;
        char* wq = (char*)d_ws + wq_off;
        hipLaunchKernelGGL(quant_x, dim3(M_DIM), dim3(256), 0, stream, x, xq, sx);
        hipLaunchKernelGGL(quant_w, dim3(N_DIM), dim3(256), 0, stream, wc, qg, wq, sw);
        const int nwg = (M_DIM / 256) * (N_DIM / 256);   // 512
        hipLaunchKernelGGL(gemm8, dim3(nwg), dim3(512), 0, stream,
                           xq, wq, sx, sw, y);
    } else {
        hipLaunchKernelGGL(fb_gemm, dim3(N_DIM / 64, M_DIM / 64), dim3(256), 0, stream,
                           x, qg, wc, y);
    }
}